// Round 6
// baseline (522.023 us; speedup 1.0000x reference)
//
#include <hip/hip_runtime.h>

// arHOCA: L=200 positions, Q=21 alphabet, H=128 hidden, B=256 batch.
// x is one-hot => all "x @ W" contractions are gather-sums over idx[b,l].
//
// DCA mask (faithful to reference): mask loop is `for i in range(Q)`, so only
// row-blocks 1..20 / col-blocks 0..19 are active; mask[d,c]=1 iff blk(c)<blk(d).
// => out_dca[b,j] = sum_{l=j/Q+1}^{20} DW[l*Q+idx[b,l], j].
//
// ws layout: idxT [200][256] int (204800B) | h1 [199][256][128] f32 (26083328B)
//            | h2T [199][128][256] f32 (26083328B)  => 52371456 B total.

#define Lc   200
#define Qc   21
#define Hc   128
#define Bc   256
#define LQc  4200
#define LM1c 199

// ---------------- K0: idxT[l][b] = argmax_c x[b,l,c] ----------------
__global__ __launch_bounds__(256) void k_idx(const float* __restrict__ x,
                                             int* __restrict__ idxT) {
    const int l = blockIdx.x;       // 0..199
    const int b = threadIdx.x;      // 0..255
    const float* p = x + ((size_t)b * Lc + l) * Qc;
    int id = 0;
#pragma unroll
    for (int c = 0; c < Qc; ++c) id = (p[c] > 0.5f) ? c : id;
    idxT[l * Bc + b] = id;          // coalesced store
}

// ---------------- K1: DCA gather + bias + out0 (w0+b0) ----------------
// out[b, j] = bias[j] + sum_{l = j/Q+1 .. 20} DW[l*Q+idx[b,l], j]  (+ w0+b0 for j<Q)
__global__ __launch_bounds__(256) void k_dca(const float* __restrict__ DW,
                                             const float* __restrict__ bias,
                                             const float* __restrict__ w0,
                                             const float* __restrict__ b0,
                                             const int* __restrict__ idxT,
                                             float* __restrict__ out) {
    const int b = blockIdx.x / 5, chunk = blockIdx.x % 5;
    const int j0 = chunk * 1024 + threadIdx.x * 4;
    if (j0 >= LQc) return;
    float a[4];
    const float4 bv = *(const float4*)(bias + j0);
    a[0] = bv.x; a[1] = bv.y; a[2] = bv.z; a[3] = bv.w;
    if (j0 < Qc) {
#pragma unroll
        for (int e = 0; e < 4; ++e) {
            int j = j0 + e;
            if (j < Qc) a[e] += w0[j] + b0[j];
        }
    }
    if (j0 < (Qc - 1) * Qc) {
        const int lmin = j0 / Qc + 1;
        for (int l = lmin; l < Qc; ++l) {
            const int iv = idxT[l * Bc + b];
            const float4 v = *(const float4*)(DW + (size_t)(l * Qc + iv) * LQc + j0);
            const int thr = l * Qc;  // contribute iff j < l*Q
            a[0] += (j0     < thr) ? v.x : 0.f;
            a[1] += (j0 + 1 < thr) ? v.y : 0.f;
            a[2] += (j0 + 2 < thr) ? v.z : 0.f;
            a[3] += (j0 + 3 < thr) ? v.w : 0.f;
        }
    }
    float4 o = {a[0], a[1], a[2], a[3]};
    *(float4*)(out + (size_t)b * LQc + j0) = o;
}

// ---------------- K2: direct-gather, named-register 2-deep pipeline ----------------
// h1[l][b][h] = lrelu(sum_{lp<=l} W1[l, lp*Q+idx[b,lp], h] + b1[l,h])
// Block = (l, 32-batch group), 128 threads (2 waves); half-wave = 8 batches;
// lane owns 8 batches x 4 h. Named float4 buffers va0..7 / vb0..7 (nothing the
// compiler can collapse) + sched_barrier fences; idx prefetched 4-7 lp ahead
// via rolling j1..j5 so no body consumes an idx loaded in the same body.
// XCD map: rank r = s*8 + (bid&7): each XCD gets every-8th l (balanced), and
// all 8 groups of one l share one XCD's L2 (their bids are congruent mod 8).
__global__ __launch_bounds__(128, 4) void k_h1(const float* __restrict__ W1,
                                               const float* __restrict__ b1,
                                               const int* __restrict__ idxT,
                                               float* __restrict__ h1) {
    const int bid = blockIdx.x;                 // 0..1599
    const int xcd = bid & 7;
    const int u   = bid >> 3;                   // 0..199
    const int s   = u >> 3, g = u & 7;          // s 0..24, g 0..7
    const int r   = s * 8 + xcd;
    if (r >= LM1c) return;
    const int l = 198 - r;                      // longest ranks spread evenly
    const int t = threadIdx.x;
    const int w = t >> 6, lane = t & 63;
    const int jb = lane >> 5, jbs = jb * 8, hq = lane & 31;
    const int wbase = g * 32 + w * 16;          // wave's 16 batches
    const int myb = wbase + (lane & 15);

    const float* Wq = W1 + (size_t)l * (LQc * Hc) + hq * 4;
    const int* ixc = idxT + myb;                // ixc[lp*Bc] = idx[b=myb, lp]

    float4 c0 = {0,0,0,0}, c1 = {0,0,0,0}, c2 = {0,0,0,0}, c3 = {0,0,0,0};
    float4 c4 = {0,0,0,0}, c5 = {0,0,0,0}, c6 = {0,0,0,0}, c7 = {0,0,0,0};
    float4 va0, va1, va2, va3, va4, va5, va6, va7;
    float4 vb0, vb1, vb2, vb3, vb4, vb5, vb6, vb7;

#define LDV(lpv, ia, i) (*(const float4*)(Wq + (size_t)((lpv) * Qc + __shfl((ia), jbs + (i))) * Hc))
#define ISSUE_A(lpv, ia) { va0=LDV(lpv,ia,0); va1=LDV(lpv,ia,1); va2=LDV(lpv,ia,2); va3=LDV(lpv,ia,3); \
                           va4=LDV(lpv,ia,4); va5=LDV(lpv,ia,5); va6=LDV(lpv,ia,6); va7=LDV(lpv,ia,7); }
#define ISSUE_B(lpv, ia) { vb0=LDV(lpv,ia,0); vb1=LDV(lpv,ia,1); vb2=LDV(lpv,ia,2); vb3=LDV(lpv,ia,3); \
                           vb4=LDV(lpv,ia,4); vb5=LDV(lpv,ia,5); vb6=LDV(lpv,ia,6); vb7=LDV(lpv,ia,7); }
#define ADD4(A, V) { A.x += V.x; A.y += V.y; A.z += V.z; A.w += V.w; }
#define CONSUME_A() { ADD4(c0,va0) ADD4(c1,va1) ADD4(c2,va2) ADD4(c3,va3) \
                      ADD4(c4,va4) ADD4(c5,va5) ADD4(c6,va6) ADD4(c7,va7) }
#define CONSUME_B() { ADD4(c0,vb0) ADD4(c1,vb1) ADD4(c2,vb2) ADD4(c3,vb3) \
                      ADD4(c4,vb4) ADD4(c5,vb5) ADD4(c6,vb6) ADD4(c7,vb7) }

    const int ia0 = ixc[0];
    int j1 = (1 <= l) ? ixc[1 * Bc] : 0;
    int j2 = (2 <= l) ? ixc[2 * Bc] : 0;
    int j3 = (3 <= l) ? ixc[3 * Bc] : 0;
    int j4 = (4 <= l) ? ixc[4 * Bc] : 0;
    int j5 = (5 <= l) ? ixc[5 * Bc] : 0;

    ISSUE_A(0, ia0);
    __builtin_amdgcn_sched_barrier(0);

    int lp = 0;
    while (lp + 1 <= l) {
        ISSUE_B(lp + 1, j1);                    // real (lp+1 <= l)
        __builtin_amdgcn_sched_barrier(0);
        CONSUME_A();                            // lp
        ISSUE_A(lp + 2, j2);                    // may be dummy; row < 4200 stays in-bounds
        __builtin_amdgcn_sched_barrier(0);
        CONSUME_B();                            // lp+1
        j1 = j3; j2 = j4; j3 = j5;
        j4 = (lp + 6 <= l) ? ixc[(lp + 6) * Bc] : 0;
        j5 = (lp + 7 <= l) ? ixc[(lp + 7) * Bc] : 0;
        lp += 2;
    }
    if (lp == l) { CONSUME_A(); }               // even-l tail
#undef LDV
#undef ISSUE_A
#undef ISSUE_B
#undef ADD4
#undef CONSUME_A
#undef CONSUME_B

    const float4 bb = *(const float4*)(b1 + l * Hc + hq * 4);
    float* outp = h1 + ((size_t)l * Bc + wbase + jbs) * Hc + hq * 4;
#define STORE(i, C) { float4 rr; \
    rr.x = C.x + bb.x; rr.y = C.y + bb.y; rr.z = C.z + bb.z; rr.w = C.w + bb.w; \
    rr.x = (rr.x >= 0.f) ? rr.x : 0.1f * rr.x; rr.y = (rr.y >= 0.f) ? rr.y : 0.1f * rr.y; \
    rr.z = (rr.z >= 0.f) ? rr.z : 0.1f * rr.z; rr.w = (rr.w >= 0.f) ? rr.w : 0.1f * rr.w; \
    *(float4*)(outp + (size_t)(i) * Hc) = rr; }
    STORE(0, c0) STORE(1, c1) STORE(2, c2) STORE(3, c3)
    STORE(4, c4) STORE(5, c5) STORE(6, c6) STORE(7, c7)
#undef STORE
}

// ---------------- K3: h2T[l][n][b] = lrelu(sum_k h1[l][b][k] * W2[l][k][n] + b2[l][n]) ----------------
// fp32 tiled GEMM: M=128 (batch half), N=128, K=128 in 8 steps of 16. 8x8 reg tile/thread.
// A-side ([b][k] row-major) is transposed into padded LDS during staging.
__global__ __launch_bounds__(256) void k_h2(const float* __restrict__ h1,
                                            const float* __restrict__ W2,
                                            const float* __restrict__ b2,
                                            float* __restrict__ h2T) {
    const int l = blockIdx.x >> 1;
    const int bbase = (blockIdx.x & 1) * 128;
    const int t = threadIdx.x;
    const int tx = t & 15, ty = t >> 4;
    __shared__ float As[16][132];
    __shared__ float Bs[16][Hc];
    __shared__ float Ts[32][Hc];
    float acc[8][8];
#pragma unroll
    for (int i = 0; i < 8; ++i)
#pragma unroll
        for (int j = 0; j < 8; ++j) acc[i][j] = 0.f;
    const int skk = t >> 4, sms = (t & 15) * 8;
    const int au = t >> 2, av4 = (t & 3) * 4;   // A-stage: m=au(+64), k-quad av4
    const float* h1l = h1 + ((size_t)l * Bc + bbase) * Hc;
    const float* W2l = W2 + (size_t)l * Hc * Hc;
    for (int ks = 0; ks < 8; ++ks) {
        const float4 a0 = *(const float4*)(h1l + (size_t)au * Hc + ks * 16 + av4);
        const float4 a1 = *(const float4*)(h1l + (size_t)(au + 64) * Hc + ks * 16 + av4);
        const int kb = ks * 16 + skk;
        *(float4*)&Bs[skk][sms]     = *(const float4*)(W2l + (size_t)kb * Hc + sms);
        *(float4*)&Bs[skk][sms + 4] = *(const float4*)(W2l + (size_t)kb * Hc + sms + 4);
        As[av4 + 0][au] = a0.x; As[av4 + 1][au] = a0.y;
        As[av4 + 2][au] = a0.z; As[av4 + 3][au] = a0.w;
        As[av4 + 0][au + 64] = a1.x; As[av4 + 1][au + 64] = a1.y;
        As[av4 + 2][au + 64] = a1.z; As[av4 + 3][au + 64] = a1.w;
        __syncthreads();
#pragma unroll
        for (int k = 0; k < 16; ++k) {
            float avr[8], bvr[8];
            *(float4*)&avr[0] = *(const float4*)&As[k][ty * 8];
            *(float4*)&avr[4] = *(const float4*)&As[k][ty * 8 + 4];
            *(float4*)&bvr[0] = *(const float4*)&Bs[k][tx * 8];
            *(float4*)&bvr[4] = *(const float4*)&Bs[k][tx * 8 + 4];
#pragma unroll
            for (int i = 0; i < 8; ++i)
#pragma unroll
                for (int j = 0; j < 8; ++j) acc[i][j] += avr[i] * bvr[j];
        }
        __syncthreads();
    }
    float bz[8];
    *(float4*)&bz[0] = *(const float4*)(b2 + l * Hc + tx * 8);
    *(float4*)&bz[4] = *(const float4*)(b2 + l * Hc + tx * 8 + 4);
    float res[8][8];
#pragma unroll
    for (int i = 0; i < 8; ++i)
#pragma unroll
        for (int j = 0; j < 8; ++j) {
            float v = acc[i][j] + bz[j];
            res[i][j] = (v >= 0.f) ? v : 0.1f * v;
        }
    // transpose-store via LDS in 4 chunks of 32 n-rows: h2T[l][n][bbase+m]
    for (int c = 0; c < 4; ++c) {
        if ((tx >> 2) == c) {
#pragma unroll
            for (int i = 0; i < 8; ++i)
#pragma unroll
                for (int j = 0; j < 8; ++j) Ts[(tx & 3) * 8 + j][ty * 8 + i] = res[i][j];
        }
        __syncthreads();
        const int r = t >> 3, m2 = (t & 7) * 16;
        float* dst = h2T + ((size_t)l * Hc + c * 32 + r) * Bc + bbase + m2;
#pragma unroll
        for (int u = 0; u < 4; ++u) *(float4*)(dst + u * 4) = *(const float4*)&Ts[r][m2 + u * 4];
        __syncthreads();
    }
}

// ---------------- K4: out[b, l+1, q] += sum_k h2T[l][k][b] * Wout[l][k][q] + bout[l][q] ----------------
__global__ __launch_bounds__(128) void k_out(const float* __restrict__ h2T,
                                             const float* __restrict__ Wout,
                                             const float* __restrict__ bout,
                                             float* __restrict__ out) {
    const int l = blockIdx.x >> 1;
    const int bh = blockIdx.x & 1;
    const int t = threadIdx.x;  // 0..127
    __shared__ float wl[Hc * Qc];
    __shared__ float bl[Qc];
    const float* wsrc = Wout + (size_t)l * Hc * Qc;
    for (int i = t; i < Hc * Qc; i += 128) wl[i] = wsrc[i];
    if (t < Qc) bl[t] = bout[l * Qc + t];
    __syncthreads();
    const int b = bh * 128 + t;
    float acc[Qc];
#pragma unroll
    for (int q = 0; q < Qc; ++q) acc[q] = bl[q];
    const float* h2l = h2T + (size_t)l * Hc * Bc + b;
    for (int k = 0; k < Hc; ++k) {
        const float av = h2l[(size_t)k * Bc];
        const float* wr = &wl[k * Qc];
#pragma unroll
        for (int q = 0; q < Qc; ++q) acc[q] += av * wr[q];
    }
    float* op = out + ((size_t)b * Lc + (l + 1)) * Qc;
#pragma unroll
    for (int q = 0; q < Qc; ++q) op[q] += acc[q];
}

extern "C" void kernel_launch(void* const* d_in, const int* in_sizes, int n_in,
                              void* d_out, int out_size, void* d_ws, size_t ws_size,
                              hipStream_t stream) {
    const float* x    = (const float*)d_in[0];
    const float* bias = (const float*)d_in[1];
    const float* DW   = (const float*)d_in[2];
    const float* w0   = (const float*)d_in[3];
    const float* b0   = (const float*)d_in[4];
    const float* W1   = (const float*)d_in[5];
    const float* b1   = (const float*)d_in[6];
    const float* W2   = (const float*)d_in[7];
    const float* b2   = (const float*)d_in[8];
    const float* Wout = (const float*)d_in[9];
    const float* bout = (const float*)d_in[10];
    float* out = (float*)d_out;

    int*   idxT = (int*)d_ws;
    float* h1   = (float*)((char*)d_ws + 204800);
    float* h2T  = (float*)((char*)d_ws + 204800 + 26083328);

    k_idx<<<Lc, 256, 0, stream>>>(x, idxT);
    k_dca<<<Bc * 5, 256, 0, stream>>>(DW, bias, w0, b0, idxT, out);
    k_h1<<<1600, 128, 0, stream>>>(W1, b1, idxT, h1);
    k_h2<<<LM1c * 2, 256, 0, stream>>>(h1, W2, b2, h2T);
    k_out<<<LM1c * 2, 128, 0, stream>>>(h2T, Wout, bout, out);
}

// Round 7
// 223.515 us; speedup vs baseline: 2.3355x; 2.3355x over previous
//
#include <hip/hip_runtime.h>

// arHOCA: L=200 positions, Q=21 alphabet, H=128 hidden, B=256 batch.
// x is one-hot => all "x @ W" contractions are gather-sums over idx[b,l].
//
// DCA mask (faithful to reference): mask loop is `for i in range(Q)`, so only
// row-blocks 1..20 / col-blocks 0..19 are active; mask[d,c]=1 iff blk(c)<blk(d).
// => out_dca[b,j] = sum_{l=j/Q+1}^{20} DW[l*Q+idx[b,l], j].
//
// ws layout: idxT [200][256] int (204800B) | h1 [199][256][128] f32 (26083328B)
//            | h2T [199][128][256] f32 (26083328B)  => 52371456 B total.

#define Lc   200
#define Qc   21
#define Hc   128
#define Bc   256
#define LQc  4200
#define LM1c 199

// ---------------- K0: idxT[l][b] = argmax_c x[b,l,c] ----------------
__global__ __launch_bounds__(256) void k_idx(const float* __restrict__ x,
                                             int* __restrict__ idxT) {
    const int l = blockIdx.x;       // 0..199
    const int b = threadIdx.x;      // 0..255
    const float* p = x + ((size_t)b * Lc + l) * Qc;
    int id = 0;
#pragma unroll
    for (int c = 0; c < Qc; ++c) id = (p[c] > 0.5f) ? c : id;
    idxT[l * Bc + b] = id;          // coalesced store
}

// ---------------- K1: DCA gather + bias + out0 (w0+b0) ----------------
// out[b, j] = bias[j] + sum_{l = j/Q+1 .. 20} DW[l*Q+idx[b,l], j]  (+ w0+b0 for j<Q)
__global__ __launch_bounds__(256) void k_dca(const float* __restrict__ DW,
                                             const float* __restrict__ bias,
                                             const float* __restrict__ w0,
                                             const float* __restrict__ b0,
                                             const int* __restrict__ idxT,
                                             float* __restrict__ out) {
    const int b = blockIdx.x / 5, chunk = blockIdx.x % 5;
    const int j0 = chunk * 1024 + threadIdx.x * 4;
    if (j0 >= LQc) return;
    float a[4];
    const float4 bv = *(const float4*)(bias + j0);
    a[0] = bv.x; a[1] = bv.y; a[2] = bv.z; a[3] = bv.w;
    if (j0 < Qc) {
#pragma unroll
        for (int e = 0; e < 4; ++e) {
            int j = j0 + e;
            if (j < Qc) a[e] += w0[j] + b0[j];
        }
    }
    if (j0 < (Qc - 1) * Qc) {
        const int lmin = j0 / Qc + 1;
        for (int l = lmin; l < Qc; ++l) {
            const int iv = idxT[l * Bc + b];
            const float4 v = *(const float4*)(DW + (size_t)(l * Qc + iv) * LQc + j0);
            const int thr = l * Qc;  // contribute iff j < l*Q
            a[0] += (j0     < thr) ? v.x : 0.f;
            a[1] += (j0 + 1 < thr) ? v.y : 0.f;
            a[2] += (j0 + 2 < thr) ? v.z : 0.f;
            a[3] += (j0 + 3 < thr) ? v.w : 0.f;
        }
    }
    float4 o = {a[0], a[1], a[2], a[3]};
    *(float4*)(out + (size_t)b * LQc + j0) = o;
}

// ---------------- K2: fine-grain TLP gather, 2-deep unroll, tiny buffers ----------------
// h1[l][b][h] = lrelu(sum_{lp<=l} W1[l, lp*Q+idx[b,lp], h] + b1[l,h])
// Block = (l, 16-batch group), 256 threads (4 waves). Lane owns 2 batches
// (ba, bb=ba+2) x 4 h (hq quad). Grid 3200 -> 12.5 waves/SIMD issued; TLP does
// the latency hiding; unroll-2 keeps only 4 float4 buffers live (~48 VGPR, no
// spill). idx loads are half-wave-uniform (broadcast). XCD map: rank
// r = s*8 + (bid&7): balanced across XCDs, all 16 groups of one l congruent
// mod 8 => share one XCD's L2 (dedup); long-l blocks dispatched first.
__global__ __launch_bounds__(256) void k_h1(const float* __restrict__ W1,
                                            const float* __restrict__ b1,
                                            const int* __restrict__ idxT,
                                            float* __restrict__ h1) {
    const int bid = blockIdx.x;           // 0..3199
    const int xcd = bid & 7;
    const int u   = bid >> 3;             // 0..399
    const int s   = u >> 4, g = u & 15;   // s 0..24, g 0..15
    const int r   = s * 8 + xcd;
    if (r >= LM1c) return;                // 16 idle blocks (r==199)
    const int l = 198 - r;
    const int t = threadIdx.x;
    const int w = t >> 6, lane = t & 63;
    const int jb = lane >> 5;             // half-wave
    const int hq = lane & 31;             // h-quad: h = hq*4..hq*4+3
    const int ba = g * 16 + w * 4 + jb;   // batch A
    const int bb = ba + 2;                // batch B

    const float* Wq = W1 + (size_t)l * (LQc * Hc) + hq * 4;
    const int* iA = idxT + ba;            // iA[lp*Bc] = idx[b=ba, lp]
    const int* iB = idxT + bb;

    float4 accA = {0, 0, 0, 0}, accB = {0, 0, 0, 0};

#define ROW(lpv, ia) (*(const float4*)(Wq + (size_t)((lpv) * Qc + (ia)) * Hc))
#define ADD4(A, V) { A.x += V.x; A.y += V.y; A.z += V.z; A.w += V.w; }

    int a1 = (1 <= l) ? iA[Bc] : 0;
    int b1v = (1 <= l) ? iB[Bc] : 0;

    float4 pA0 = ROW(0, iA[0]);
    float4 pB0 = ROW(0, iB[0]);

    int lp = 0;
    while (lp + 1 <= l) {
        // prefetch idx two/three steps ahead (dummy -> lp index 0, in-bounds)
        const int lp2 = (lp + 2 <= l) ? lp + 2 : 0;
        const int lp3 = (lp + 3 <= l) ? lp + 3 : 0;
        const int a2 = iA[lp2 * Bc];
        const int b2 = iB[lp2 * Bc];
        const int a3 = iA[lp3 * Bc];
        const int b3 = iB[lp3 * Bc];
        // issue set1 (lp+1, real), consume set0 (lp)
        float4 pA1 = ROW(lp + 1, a1);
        float4 pB1 = ROW(lp + 1, b1v);
        ADD4(accA, pA0) ADD4(accB, pB0)
        // issue set0 (lp+2; dummy reloads row of lp=0, never consumed)
        pA0 = ROW(lp2, a2);
        pB0 = ROW(lp2, b2);
        ADD4(accA, pA1) ADD4(accB, pB1)
        a1 = a3; b1v = b3;
        lp += 2;
    }
    if (lp == l) { ADD4(accA, pA0) ADD4(accB, pB0) }  // even-l tail
#undef ROW
#undef ADD4

    const float4 bbv = *(const float4*)(b1 + l * Hc + hq * 4);
    float4 rA, rB;
    rA.x = accA.x + bbv.x; rA.y = accA.y + bbv.y; rA.z = accA.z + bbv.z; rA.w = accA.w + bbv.w;
    rB.x = accB.x + bbv.x; rB.y = accB.y + bbv.y; rB.z = accB.z + bbv.z; rB.w = accB.w + bbv.w;
    rA.x = (rA.x >= 0.f) ? rA.x : 0.1f * rA.x; rA.y = (rA.y >= 0.f) ? rA.y : 0.1f * rA.y;
    rA.z = (rA.z >= 0.f) ? rA.z : 0.1f * rA.z; rA.w = (rA.w >= 0.f) ? rA.w : 0.1f * rA.w;
    rB.x = (rB.x >= 0.f) ? rB.x : 0.1f * rB.x; rB.y = (rB.y >= 0.f) ? rB.y : 0.1f * rB.y;
    rB.z = (rB.z >= 0.f) ? rB.z : 0.1f * rB.z; rB.w = (rB.w >= 0.f) ? rB.w : 0.1f * rB.w;
    *(float4*)(h1 + ((size_t)l * Bc + ba) * Hc + hq * 4) = rA;  // 512B/half-wave
    *(float4*)(h1 + ((size_t)l * Bc + bb) * Hc + hq * 4) = rB;
}

// ---------------- K3: h2T[l][n][b] = lrelu(sum_k h1[l][b][k] * W2[l][k][n] + b2[l][n]) ----------------
// fp32 tiled GEMM: M=128 (batch half), N=128, K=128 in 8 steps of 16. 8x8 reg tile/thread.
// A-side ([b][k] row-major) is transposed into padded LDS during staging.
__global__ __launch_bounds__(256) void k_h2(const float* __restrict__ h1,
                                            const float* __restrict__ W2,
                                            const float* __restrict__ b2,
                                            float* __restrict__ h2T) {
    const int l = blockIdx.x >> 1;
    const int bbase = (blockIdx.x & 1) * 128;
    const int t = threadIdx.x;
    const int tx = t & 15, ty = t >> 4;
    __shared__ float As[16][132];
    __shared__ float Bs[16][Hc];
    __shared__ float Ts[32][Hc];
    float acc[8][8];
#pragma unroll
    for (int i = 0; i < 8; ++i)
#pragma unroll
        for (int j = 0; j < 8; ++j) acc[i][j] = 0.f;
    const int skk = t >> 4, sms = (t & 15) * 8;
    const int au = t >> 2, av4 = (t & 3) * 4;   // A-stage: m=au(+64), k-quad av4
    const float* h1l = h1 + ((size_t)l * Bc + bbase) * Hc;
    const float* W2l = W2 + (size_t)l * Hc * Hc;
    for (int ks = 0; ks < 8; ++ks) {
        const float4 a0 = *(const float4*)(h1l + (size_t)au * Hc + ks * 16 + av4);
        const float4 a1 = *(const float4*)(h1l + (size_t)(au + 64) * Hc + ks * 16 + av4);
        const int kb = ks * 16 + skk;
        *(float4*)&Bs[skk][sms]     = *(const float4*)(W2l + (size_t)kb * Hc + sms);
        *(float4*)&Bs[skk][sms + 4] = *(const float4*)(W2l + (size_t)kb * Hc + sms + 4);
        As[av4 + 0][au] = a0.x; As[av4 + 1][au] = a0.y;
        As[av4 + 2][au] = a0.z; As[av4 + 3][au] = a0.w;
        As[av4 + 0][au + 64] = a1.x; As[av4 + 1][au + 64] = a1.y;
        As[av4 + 2][au + 64] = a1.z; As[av4 + 3][au + 64] = a1.w;
        __syncthreads();
#pragma unroll
        for (int k = 0; k < 16; ++k) {
            float avr[8], bvr[8];
            *(float4*)&avr[0] = *(const float4*)&As[k][ty * 8];
            *(float4*)&avr[4] = *(const float4*)&As[k][ty * 8 + 4];
            *(float4*)&bvr[0] = *(const float4*)&Bs[k][tx * 8];
            *(float4*)&bvr[4] = *(const float4*)&Bs[k][tx * 8 + 4];
#pragma unroll
            for (int i = 0; i < 8; ++i)
#pragma unroll
                for (int j = 0; j < 8; ++j) acc[i][j] += avr[i] * bvr[j];
        }
        __syncthreads();
    }
    float bz[8];
    *(float4*)&bz[0] = *(const float4*)(b2 + l * Hc + tx * 8);
    *(float4*)&bz[4] = *(const float4*)(b2 + l * Hc + tx * 8 + 4);
    float res[8][8];
#pragma unroll
    for (int i = 0; i < 8; ++i)
#pragma unroll
        for (int j = 0; j < 8; ++j) {
            float v = acc[i][j] + bz[j];
            res[i][j] = (v >= 0.f) ? v : 0.1f * v;
        }
    // transpose-store via LDS in 4 chunks of 32 n-rows: h2T[l][n][bbase+m]
    for (int c = 0; c < 4; ++c) {
        if ((tx >> 2) == c) {
#pragma unroll
            for (int i = 0; i < 8; ++i)
#pragma unroll
                for (int j = 0; j < 8; ++j) Ts[(tx & 3) * 8 + j][ty * 8 + i] = res[i][j];
        }
        __syncthreads();
        const int r = t >> 3, m2 = (t & 7) * 16;
        float* dst = h2T + ((size_t)l * Hc + c * 32 + r) * Bc + bbase + m2;
#pragma unroll
        for (int u = 0; u < 4; ++u) *(float4*)(dst + u * 4) = *(const float4*)&Ts[r][m2 + u * 4];
        __syncthreads();
    }
}

// ---------------- K4: out[b, l+1, q] += sum_k h2T[l][k][b] * Wout[l][k][q] + bout[l][q] ----------------
__global__ __launch_bounds__(128) void k_out(const float* __restrict__ h2T,
                                             const float* __restrict__ Wout,
                                             const float* __restrict__ bout,
                                             float* __restrict__ out) {
    const int l = blockIdx.x >> 1;
    const int bh = blockIdx.x & 1;
    const int t = threadIdx.x;  // 0..127
    __shared__ float wl[Hc * Qc];
    __shared__ float bl[Qc];
    const float* wsrc = Wout + (size_t)l * Hc * Qc;
    for (int i = t; i < Hc * Qc; i += 128) wl[i] = wsrc[i];
    if (t < Qc) bl[t] = bout[l * Qc + t];
    __syncthreads();
    const int b = bh * 128 + t;
    float acc[Qc];
#pragma unroll
    for (int q = 0; q < Qc; ++q) acc[q] = bl[q];
    const float* h2l = h2T + (size_t)l * Hc * Bc + b;
    for (int k = 0; k < Hc; ++k) {
        const float av = h2l[(size_t)k * Bc];
        const float* wr = &wl[k * Qc];
#pragma unroll
        for (int q = 0; q < Qc; ++q) acc[q] += av * wr[q];
    }
    float* op = out + ((size_t)b * Lc + (l + 1)) * Qc;
#pragma unroll
    for (int q = 0; q < Qc; ++q) op[q] += acc[q];
}

extern "C" void kernel_launch(void* const* d_in, const int* in_sizes, int n_in,
                              void* d_out, int out_size, void* d_ws, size_t ws_size,
                              hipStream_t stream) {
    const float* x    = (const float*)d_in[0];
    const float* bias = (const float*)d_in[1];
    const float* DW   = (const float*)d_in[2];
    const float* w0   = (const float*)d_in[3];
    const float* b0   = (const float*)d_in[4];
    const float* W1   = (const float*)d_in[5];
    const float* b1   = (const float*)d_in[6];
    const float* W2   = (const float*)d_in[7];
    const float* b2   = (const float*)d_in[8];
    const float* Wout = (const float*)d_in[9];
    const float* bout = (const float*)d_in[10];
    float* out = (float*)d_out;

    int*   idxT = (int*)d_ws;
    float* h1   = (float*)((char*)d_ws + 204800);
    float* h2T  = (float*)((char*)d_ws + 204800 + 26083328);

    k_idx<<<Lc, 256, 0, stream>>>(x, idxT);
    k_dca<<<Bc * 5, 256, 0, stream>>>(DW, bias, w0, b0, idxT, out);
    k_h1<<<3200, 256, 0, stream>>>(W1, b1, idxT, h1);
    k_h2<<<LM1c * 2, 256, 0, stream>>>(h1, W2, b2, h2T);
    k_out<<<LM1c * 2, 128, 0, stream>>>(h2T, Wout, bout, out);
}